// Round 1
// baseline (2969.331 us; speedup 1.0000x reference)
//
#include <hip/hip_runtime.h>
#include <math.h>

#define N_NODES 100000
#define N_EDGES 1600000
#define HDIM 128
#define NBLK 16

// ---------------- Edge kernel, layer 1 ----------------
// 128 threads per edge; thread t computes msg[e][t], t = b*8+o, b=t>>3, o=t&7
// msg[e][b*8+o] = sum_i h[src[e]][b*8+i] * W1[etype[e]][b][i][o]
__global__ __launch_bounds__(256) void edge_layer1(
    const int* __restrict__ src, const int* __restrict__ dst,
    const int* __restrict__ etype, const float* __restrict__ norm,
    const int* __restrict__ node_ids,
    const float* __restrict__ emb, const float* __restrict__ W,
    float* __restrict__ agg) {
  int gid = blockIdx.x * 256 + threadIdx.x;
  int e = gid >> 7;
  if (e >= N_EDGES) return;
  int t = gid & 127;
  int s = src[e], d = dst[e], r = etype[e];
  float nrm = norm[e];
  int b = t >> 3, o = t & 7;
  const float* hp = emb + (long)node_ids[s] * HDIM + b * 8;
  const float* Wp = W + ((r * NBLK + b) * 8) * 8 + o;  // stride 8 floats per i
  float4 h0 = *(const float4*)hp;
  float4 h1 = *(const float4*)(hp + 4);
  float acc = h0.x * Wp[0]  + h0.y * Wp[8]  + h0.z * Wp[16] + h0.w * Wp[24]
            + h1.x * Wp[32] + h1.y * Wp[40] + h1.z * Wp[48] + h1.w * Wp[56];
  atomicAdd(&agg[(long)d * HDIM + t], acc * nrm);
}

// ---------------- Edge kernel, layer 2 ----------------
// 256 threads per edge; t = b*16+o, b=t>>4, o=t&15
// msg[e][b*16+o] = sum_i h1[src[e]][b*8+i] * W2[etype[e]][b][i][o]
__global__ __launch_bounds__(256) void edge_layer2(
    const int* __restrict__ src, const int* __restrict__ dst,
    const int* __restrict__ etype, const float* __restrict__ norm,
    const float* __restrict__ h1, const float* __restrict__ W,
    float* __restrict__ agg) {
  int gid = blockIdx.x * 256 + threadIdx.x;
  int e = gid >> 8;
  if (e >= N_EDGES) return;
  int t = gid & 255;
  int s = src[e], d = dst[e], r = etype[e];
  float nrm = norm[e];
  int b = t >> 4, o = t & 15;
  const float* hp = h1 + (long)s * HDIM + b * 8;
  const float* Wp = W + ((r * NBLK + b) * 8) * 16 + o;  // stride 16 floats per i
  float4 h0 = *(const float4*)hp;
  float4 h1v = *(const float4*)(hp + 4);
  float acc = h0.x  * Wp[0]  + h0.y  * Wp[16] + h0.z  * Wp[32] + h0.w  * Wp[48]
            + h1v.x * Wp[64] + h1v.y * Wp[80] + h1v.z * Wp[96] + h1v.w * Wp[112];
  atomicAdd(&agg[(long)d * 256 + t], acc * nrm);
}

// ---------------- Node kernel, layer 1 ----------------
// h1[n][o] = relu(agg1[n][o] + b1[o] + sum_i emb[node_ids[n]][i]*loop1[i][o])
// loop1 (128x128, 64KB) staged in LDS; 256 threads process 2 nodes per iter.
__global__ __launch_bounds__(256) void node_layer1(
    const int* __restrict__ node_ids, const float* __restrict__ emb,
    const float* __restrict__ loop1, const float* __restrict__ agg1,
    const float* __restrict__ bias, float* __restrict__ h1out) {
  __shared__ float L[HDIM * HDIM];
  __shared__ float hs[2][HDIM];
  for (int idx = threadIdx.x; idx < HDIM * HDIM; idx += 256) L[idx] = loop1[idx];
  __syncthreads();
  int o = threadIdx.x & 127;
  int sub = threadIdx.x >> 7;
  for (int base = blockIdx.x * 2; base < N_NODES; base += gridDim.x * 2) {
    int n = base + sub;
    if (n < N_NODES) hs[sub][o] = emb[(long)node_ids[n] * HDIM + o];
    __syncthreads();
    if (n < N_NODES) {
      float acc = 0.f;
#pragma unroll
      for (int i = 0; i < HDIM; ++i) acc = fmaf(hs[sub][i], L[i * HDIM + o], acc);
      float v = acc + bias[o] + agg1[(long)n * HDIM + o];
      h1out[(long)n * HDIM + o] = fmaxf(v, 0.f);
    }
    __syncthreads();
  }
}

// ---------------- Node kernel, layer 2, columns [0,128) -> m, written to d_out ----------------
__global__ __launch_bounds__(256) void node_layer2a(
    const float* __restrict__ h1, const float* __restrict__ loop2,
    const float* __restrict__ agg2, const float* __restrict__ bias2,
    float* __restrict__ outm) {
  __shared__ float L[HDIM * HDIM];
  __shared__ float hs[2][HDIM];
  for (int idx = threadIdx.x; idx < HDIM * HDIM; idx += 256) {
    int i = idx >> 7, oo = idx & 127;
    L[idx] = loop2[i * 256 + oo];
  }
  __syncthreads();
  int o = threadIdx.x & 127;
  int sub = threadIdx.x >> 7;
  for (int base = blockIdx.x * 2; base < N_NODES; base += gridDim.x * 2) {
    int n = base + sub;
    if (n < N_NODES) hs[sub][o] = h1[(long)n * HDIM + o];
    __syncthreads();
    if (n < N_NODES) {
      float acc = 0.f;
#pragma unroll
      for (int i = 0; i < HDIM; ++i) acc = fmaf(hs[sub][i], L[i * HDIM + o], acc);
      outm[(long)n * HDIM + o] = acc + bias2[o] + agg2[(long)n * 256 + o];
    }
    __syncthreads();
  }
}

// ---------------- Node kernel, layer 2, columns [128,256) -> hv; fused gaussian sample ----------------
// z = m + sqrt(softplus(hv)+1e-8)*eps ; m read from d_out (written by node_layer2a), z overwrites d_out
__global__ __launch_bounds__(256) void node_layer2b(
    const float* __restrict__ h1, const float* __restrict__ loop2,
    const float* __restrict__ agg2, const float* __restrict__ bias2,
    const float* __restrict__ eps, float* __restrict__ out) {
  __shared__ float L[HDIM * HDIM];
  __shared__ float hs[2][HDIM];
  for (int idx = threadIdx.x; idx < HDIM * HDIM; idx += 256) {
    int i = idx >> 7, oo = idx & 127;
    L[idx] = loop2[i * 256 + 128 + oo];
  }
  __syncthreads();
  int o = threadIdx.x & 127;
  int sub = threadIdx.x >> 7;
  for (int base = blockIdx.x * 2; base < N_NODES; base += gridDim.x * 2) {
    int n = base + sub;
    if (n < N_NODES) hs[sub][o] = h1[(long)n * HDIM + o];
    __syncthreads();
    if (n < N_NODES) {
      float acc = 0.f;
#pragma unroll
      for (int i = 0; i < HDIM; ++i) acc = fmaf(hs[sub][i], L[i * HDIM + o], acc);
      float hv = acc + bias2[128 + o] + agg2[(long)n * 256 + 128 + o];
      // numerically-stable softplus
      float sp = fmaxf(hv, 0.f) + log1pf(expf(-fabsf(hv)));
      float var = sp + 1e-8f;
      long off = (long)n * HDIM + o;
      out[off] = out[off] + sqrtf(var) * eps[off];
    }
    __syncthreads();
  }
}

extern "C" void kernel_launch(void* const* d_in, const int* in_sizes, int n_in,
                              void* d_out, int out_size, void* d_ws, size_t ws_size,
                              hipStream_t stream) {
  const int* node_ids = (const int*)d_in[0];
  const int* src      = (const int*)d_in[1];
  const int* dst      = (const int*)d_in[2];
  const int* etype    = (const int*)d_in[3];
  const float* norm   = (const float*)d_in[4];
  const float* emb    = (const float*)d_in[5];
  const float* W1     = (const float*)d_in[6];
  const float* loop1  = (const float*)d_in[7];
  const float* b1     = (const float*)d_in[8];
  const float* W2     = (const float*)d_in[9];
  const float* loop2  = (const float*)d_in[10];
  const float* b2     = (const float*)d_in[11];
  const float* eps    = (const float*)d_in[12];
  float* out = (float*)d_out;

  char* ws = (char*)d_ws;
  // Layout: [0, N*256*4) = agg2 (agg1 reuses its first half; agg1 is dead
  // before agg2's memset); [N*256*4, +N*128*4) = h1.
  float* agg1 = (float*)ws;
  float* agg2 = (float*)ws;
  float* h1   = (float*)(ws + (size_t)N_NODES * 256 * 4);

  // ---- layer 1 ----
  hipMemsetAsync(agg1, 0, (size_t)N_NODES * HDIM * 4, stream);
  {
    int total = N_EDGES * 128;               // 204.8M threads
    edge_layer1<<<total / 256, 256, 0, stream>>>(src, dst, etype, norm, node_ids,
                                                 emb, W1, agg1);
  }
  node_layer1<<<512, 256, 0, stream>>>(node_ids, emb, loop1, agg1, b1, h1);

  // ---- layer 2 ----
  hipMemsetAsync(agg2, 0, (size_t)N_NODES * 256 * 4, stream);
  {
    // 256 threads/edge -> one block per edge
    edge_layer2<<<N_EDGES, 256, 0, stream>>>(src, dst, etype, norm, h1, W2, agg2);
  }
  node_layer2a<<<512, 256, 0, stream>>>(h1, loop2, agg2, b2, out);
  node_layer2b<<<512, 256, 0, stream>>>(h1, loop2, agg2, b2, eps, out);
}

// Round 2
// 2016.282 us; speedup vs baseline: 1.4727x; 1.4727x over previous
//
#include <hip/hip_runtime.h>
#include <math.h>

#define N_NODES 100000
#define N_EDGES 1600000
#define HDIM 128
#define NBLK 16

// ================= CSR build (dst -> edge list) =================
__global__ __launch_bounds__(256) void hist_deg(const int* __restrict__ dst,
                                                int* __restrict__ deg) {
  int e = blockIdx.x * 256 + threadIdx.x;
  if (e < N_EDGES) atomicAdd(&deg[dst[e]], 1);
}

// single-block exclusive scan over deg -> offsets (100K elements)
__global__ __launch_bounds__(1024) void scan_offsets(const int* __restrict__ deg,
                                                     int* __restrict__ offsets) {
  __shared__ int buf[1024];
  __shared__ int carry_s;
  if (threadIdx.x == 0) carry_s = 0;
  __syncthreads();
  for (int base = 0; base < N_NODES; base += 1024) {
    int i = base + threadIdx.x;
    int v = (i < N_NODES) ? deg[i] : 0;
    int x = v;
    buf[threadIdx.x] = x;
    __syncthreads();
#pragma unroll
    for (int s = 1; s < 1024; s <<= 1) {
      int add = (threadIdx.x >= (unsigned)s) ? buf[threadIdx.x - s] : 0;
      __syncthreads();
      x += add;
      buf[threadIdx.x] = x;
      __syncthreads();
    }
    int carry = carry_s;
    if (i < N_NODES) offsets[i] = carry + x - v;  // exclusive
    __syncthreads();
    if (threadIdx.x == 1023) carry_s = carry + x;
    __syncthreads();
  }
}

__global__ __launch_bounds__(256) void scatter_edges(const int* __restrict__ dst,
                                                     const int* __restrict__ offsets,
                                                     int* __restrict__ cursor,
                                                     int* __restrict__ edge_ids) {
  int e = blockIdx.x * 256 + threadIdx.x;
  if (e >= N_EDGES) return;
  int d = dst[e];
  int pos = offsets[d] + atomicAdd(&cursor[d], 1);
  edge_ids[pos] = e;
}

// ================= Layer-1 aggregation: one wave per node =================
// lane l: block b = l>>2, cols o2 = (l&3)*2 .. +1  (16 blocks * 8 cols = 128)
__global__ __launch_bounds__(256) void agg_layer1(
    const int* __restrict__ edge_ids, const int* __restrict__ offsets,
    const int* __restrict__ deg, const int* __restrict__ src,
    const int* __restrict__ etype, const float* __restrict__ norm,
    const int* __restrict__ node_ids, const float* __restrict__ emb,
    const float* __restrict__ W, float* __restrict__ agg) {
  int n = blockIdx.x * 4 + (threadIdx.x >> 6);
  if (n >= N_NODES) return;
  int l = threadIdx.x & 63;
  int b = l >> 2, o2 = (l & 3) * 2;
  int start = offsets[n], cnt = deg[n];
  float acc0 = 0.f, acc1 = 0.f;
  for (int k = 0; k < cnt; ++k) {
    int e = edge_ids[start + k];
    int s = src[e];
    int r = etype[e];
    float nrm = norm[e];
    const float* hp = emb + (long)node_ids[s] * HDIM + b * 8;
    float4 ha = *(const float4*)hp;
    float4 hb = *(const float4*)(hp + 4);
    float h[8] = {ha.x, ha.y, ha.z, ha.w, hb.x, hb.y, hb.z, hb.w};
    const float* Wp = W + ((r * NBLK + b) * 8) * 8 + o2;
    float p0 = 0.f, p1 = 0.f;
#pragma unroll
    for (int i = 0; i < 8; ++i) {
      float2 w = *(const float2*)(Wp + i * 8);
      p0 = fmaf(h[i], w.x, p0);
      p1 = fmaf(h[i], w.y, p1);
    }
    acc0 = fmaf(p0, nrm, acc0);
    acc1 = fmaf(p1, nrm, acc1);
  }
  float2 res = {acc0, acc1};
  *(float2*)(agg + (long)n * HDIM + l * 2) = res;
}

// ================= Layer-2 aggregation: one wave per node =================
// lane l: block b = l>>2, cols o4 = (l&3)*4 .. +3  (16 blocks * 16 cols = 256)
__global__ __launch_bounds__(256) void agg_layer2(
    const int* __restrict__ edge_ids, const int* __restrict__ offsets,
    const int* __restrict__ deg, const int* __restrict__ src,
    const int* __restrict__ etype, const float* __restrict__ norm,
    const float* __restrict__ h1, const float* __restrict__ W,
    float* __restrict__ agg) {
  int n = blockIdx.x * 4 + (threadIdx.x >> 6);
  if (n >= N_NODES) return;
  int l = threadIdx.x & 63;
  int b = l >> 2, o4 = (l & 3) * 4;
  int start = offsets[n], cnt = deg[n];
  float ax = 0.f, ay = 0.f, az = 0.f, aw = 0.f;
  for (int k = 0; k < cnt; ++k) {
    int e = edge_ids[start + k];
    int s = src[e];
    int r = etype[e];
    float nrm = norm[e];
    const float* hp = h1 + (long)s * HDIM + b * 8;
    float4 ha = *(const float4*)hp;
    float4 hb = *(const float4*)(hp + 4);
    float h[8] = {ha.x, ha.y, ha.z, ha.w, hb.x, hb.y, hb.z, hb.w};
    const float* Wp = W + ((r * NBLK + b) * 8) * 16 + o4;
    float px = 0.f, py = 0.f, pz = 0.f, pw = 0.f;
#pragma unroll
    for (int i = 0; i < 8; ++i) {
      float4 w = *(const float4*)(Wp + i * 16);
      px = fmaf(h[i], w.x, px);
      py = fmaf(h[i], w.y, py);
      pz = fmaf(h[i], w.z, pz);
      pw = fmaf(h[i], w.w, pw);
    }
    ax = fmaf(px, nrm, ax);
    ay = fmaf(py, nrm, ay);
    az = fmaf(pz, nrm, az);
    aw = fmaf(pw, nrm, aw);
  }
  float4 res = {ax, ay, az, aw};
  *(float4*)(agg + (long)n * 256 + l * 4) = res;
}

// ================= Node kernels (dense self-loop + epilogue) =================
__global__ __launch_bounds__(256) void node_layer1(
    const int* __restrict__ node_ids, const float* __restrict__ emb,
    const float* __restrict__ loop1, const float* __restrict__ agg1,
    const float* __restrict__ bias, float* __restrict__ h1out) {
  __shared__ float L[HDIM * HDIM];
  __shared__ float hs[2][HDIM];
  for (int idx = threadIdx.x; idx < HDIM * HDIM; idx += 256) L[idx] = loop1[idx];
  __syncthreads();
  int o = threadIdx.x & 127;
  int sub = threadIdx.x >> 7;
  for (int base = blockIdx.x * 2; base < N_NODES; base += gridDim.x * 2) {
    int n = base + sub;
    if (n < N_NODES) hs[sub][o] = emb[(long)node_ids[n] * HDIM + o];
    __syncthreads();
    if (n < N_NODES) {
      float acc = 0.f;
#pragma unroll
      for (int i = 0; i < HDIM; ++i) acc = fmaf(hs[sub][i], L[i * HDIM + o], acc);
      float v = acc + bias[o] + agg1[(long)n * HDIM + o];
      h1out[(long)n * HDIM + o] = fmaxf(v, 0.f);
    }
    __syncthreads();
  }
}

__global__ __launch_bounds__(256) void node_layer2a(
    const float* __restrict__ h1, const float* __restrict__ loop2,
    const float* __restrict__ agg2, const float* __restrict__ bias2,
    float* __restrict__ outm) {
  __shared__ float L[HDIM * HDIM];
  __shared__ float hs[2][HDIM];
  for (int idx = threadIdx.x; idx < HDIM * HDIM; idx += 256) {
    int i = idx >> 7, oo = idx & 127;
    L[idx] = loop2[i * 256 + oo];
  }
  __syncthreads();
  int o = threadIdx.x & 127;
  int sub = threadIdx.x >> 7;
  for (int base = blockIdx.x * 2; base < N_NODES; base += gridDim.x * 2) {
    int n = base + sub;
    if (n < N_NODES) hs[sub][o] = h1[(long)n * HDIM + o];
    __syncthreads();
    if (n < N_NODES) {
      float acc = 0.f;
#pragma unroll
      for (int i = 0; i < HDIM; ++i) acc = fmaf(hs[sub][i], L[i * HDIM + o], acc);
      outm[(long)n * HDIM + o] = acc + bias2[o] + agg2[(long)n * 256 + o];
    }
    __syncthreads();
  }
}

__global__ __launch_bounds__(256) void node_layer2b(
    const float* __restrict__ h1, const float* __restrict__ loop2,
    const float* __restrict__ agg2, const float* __restrict__ bias2,
    const float* __restrict__ eps, float* __restrict__ out) {
  __shared__ float L[HDIM * HDIM];
  __shared__ float hs[2][HDIM];
  for (int idx = threadIdx.x; idx < HDIM * HDIM; idx += 256) {
    int i = idx >> 7, oo = idx & 127;
    L[idx] = loop2[i * 256 + 128 + oo];
  }
  __syncthreads();
  int o = threadIdx.x & 127;
  int sub = threadIdx.x >> 7;
  for (int base = blockIdx.x * 2; base < N_NODES; base += gridDim.x * 2) {
    int n = base + sub;
    if (n < N_NODES) hs[sub][o] = h1[(long)n * HDIM + o];
    __syncthreads();
    if (n < N_NODES) {
      float acc = 0.f;
#pragma unroll
      for (int i = 0; i < HDIM; ++i) acc = fmaf(hs[sub][i], L[i * HDIM + o], acc);
      float hv = acc + bias2[128 + o] + agg2[(long)n * 256 + 128 + o];
      float sp = fmaxf(hv, 0.f) + log1pf(expf(-fabsf(hv)));
      float var = sp + 1e-8f;
      long off = (long)n * HDIM + o;
      out[off] = out[off] + sqrtf(var) * eps[off];
    }
    __syncthreads();
  }
}

extern "C" void kernel_launch(void* const* d_in, const int* in_sizes, int n_in,
                              void* d_out, int out_size, void* d_ws, size_t ws_size,
                              hipStream_t stream) {
  const int* node_ids = (const int*)d_in[0];
  const int* src      = (const int*)d_in[1];
  const int* dst      = (const int*)d_in[2];
  const int* etype    = (const int*)d_in[3];
  const float* norm   = (const float*)d_in[4];
  const float* emb    = (const float*)d_in[5];
  const float* W1     = (const float*)d_in[6];
  const float* loop1  = (const float*)d_in[7];
  const float* b1     = (const float*)d_in[8];
  const float* W2     = (const float*)d_in[9];
  const float* loop2  = (const float*)d_in[10];
  const float* b2     = (const float*)d_in[11];
  const float* eps    = (const float*)d_in[12];
  float* out = (float*)d_out;

  char* ws = (char*)d_ws;
  size_t off = 0;
  int* deg      = (int*)(ws + off); off += (size_t)N_NODES * 4;
  int* offsets  = (int*)(ws + off); off += (size_t)N_NODES * 4;
  int* cursor   = (int*)(ws + off); off += (size_t)N_NODES * 4;
  int* edge_ids = (int*)(ws + off); off += (size_t)N_EDGES * 4;
  float* agg2   = (float*)(ws + off); off += (size_t)N_NODES * 256 * 4;
  float* h1     = (float*)(ws + off); off += (size_t)N_NODES * HDIM * 4;
  // agg1 lives in d_out (dead before node_layer2a overwrites it)
  float* agg1 = out;

  // ---- CSR build ----
  hipMemsetAsync(deg, 0, (size_t)N_NODES * 8, stream);  // deg + offsets... only deg+cursor needed
  hipMemsetAsync(cursor, 0, (size_t)N_NODES * 4, stream);
  hist_deg<<<(N_EDGES + 255) / 256, 256, 0, stream>>>(dst, deg);
  scan_offsets<<<1, 1024, 0, stream>>>(deg, offsets);
  scatter_edges<<<(N_EDGES + 255) / 256, 256, 0, stream>>>(dst, offsets, cursor, edge_ids);

  // ---- layer 1 ----
  agg_layer1<<<(N_NODES + 3) / 4, 256, 0, stream>>>(edge_ids, offsets, deg, src,
                                                    etype, norm, node_ids, emb, W1, agg1);
  node_layer1<<<512, 256, 0, stream>>>(node_ids, emb, loop1, agg1, b1, h1);

  // ---- layer 2 ----
  agg_layer2<<<(N_NODES + 3) / 4, 256, 0, stream>>>(edge_ids, offsets, deg, src,
                                                    etype, norm, h1, W2, agg2);
  node_layer2a<<<512, 256, 0, stream>>>(h1, loop2, agg2, b2, out);
  node_layer2b<<<512, 256, 0, stream>>>(h1, loop2, agg2, b2, eps, out);
}

// Round 3
// 1945.002 us; speedup vs baseline: 1.5266x; 1.0366x over previous
//
#include <hip/hip_runtime.h>
#include <math.h>

#define N_NODES 100000
#define N_EDGES 1600000
#define HDIM 128
#define NBLK 16

typedef unsigned short ushort_t;
typedef unsigned int uint_t;

__device__ __forceinline__ ushort_t f2bf(float f) {
  uint_t u = __float_as_uint(f);
  u = (u + 0x7fffu + ((u >> 16) & 1u)) >> 16;  // round-to-nearest-even
  return (ushort_t)u;
}
__device__ __forceinline__ float bf_lo(uint_t w) { return __uint_as_float(w << 16); }
__device__ __forceinline__ float bf_hi(uint_t w) { return __uint_as_float(w & 0xffff0000u); }

// ================= CSR build (dst -> packed edge records) =================
__global__ __launch_bounds__(256) void hist_deg(const int* __restrict__ dst,
                                                int* __restrict__ deg) {
  int e = blockIdx.x * 256 + threadIdx.x;
  if (e < N_EDGES) atomicAdd(&deg[dst[e]], 1);
}

// single-block scan via wave shuffles (exclusive offsets)
__global__ __launch_bounds__(1024) void scan_offsets(const int* __restrict__ deg,
                                                     int* __restrict__ offsets) {
  __shared__ int wsum[16];
  __shared__ int carry_s;
  int tid = threadIdx.x, lane = tid & 63, wid = tid >> 6;
  if (tid == 0) carry_s = 0;
  __syncthreads();
  for (int base = 0; base < N_NODES; base += 1024) {
    int i = base + tid;
    int v = (i < N_NODES) ? deg[i] : 0;
    int x = v;
#pragma unroll
    for (int s = 1; s < 64; s <<= 1) {
      int t = __shfl_up(x, s);
      if (lane >= s) x += t;
    }
    if (lane == 63) wsum[wid] = x;
    __syncthreads();
    if (wid == 0) {
      int y = (lane < 16) ? wsum[lane] : 0;
#pragma unroll
      for (int s = 1; s < 16; s <<= 1) {
        int t = __shfl_up(y, s);
        if (lane >= s) y += t;
      }
      if (lane < 16) wsum[lane] = y;
    }
    __syncthreads();
    int carry = carry_s;
    int wbase = (wid > 0) ? wsum[wid - 1] : 0;
    if (i < N_NODES) offsets[i] = carry + wbase + (x - v);
    __syncthreads();
    if (tid == 0) carry_s = carry + wsum[15];
    __syncthreads();
  }
}

// writes packed records {src, etype, norm_bits, 0} into CSR position
__global__ __launch_bounds__(256) void scatter_rec(
    const int* __restrict__ src, const int* __restrict__ dst,
    const int* __restrict__ etype, const float* __restrict__ norm,
    const int* __restrict__ offsets, int* __restrict__ cursor,
    int4* __restrict__ rec) {
  int e = blockIdx.x * 256 + threadIdx.x;
  if (e >= N_EDGES) return;
  int d = dst[e];
  int pos = offsets[d] + atomicAdd(&cursor[d], 1);
  rec[pos] = make_int4(src[e], etype[e], __float_as_int(norm[e]), 0);
}

// bf16 copy of gathered embeddings: h0b[n] = bf16(emb[node_ids[n]])
__global__ __launch_bounds__(256) void conv_h0(const int* __restrict__ node_ids,
                                               const float* __restrict__ emb,
                                               ushort_t* __restrict__ h0b) {
  long gid = (long)blockIdx.x * 256 + threadIdx.x;
  if (gid >= (long)N_NODES * HDIM) return;
  int n = (int)(gid >> 7);
  int o = (int)(gid & 127);
  h0b[gid] = f2bf(emb[(long)node_ids[n] * HDIM + o]);
}

// ================= Layer-1 aggregation: one wave per node =================
// lane l: block b = l>>2, cols o2 = (l&3)*2 (16 blocks * 8 cols = 128)
__global__ __launch_bounds__(256) void agg_layer1(
    const int4* __restrict__ rec, const int* __restrict__ offsets,
    const int* __restrict__ deg, const ushort_t* __restrict__ h0b,
    const float* __restrict__ W, float* __restrict__ agg) {
  int n = blockIdx.x * 4 + (threadIdx.x >> 6);
  if (n >= N_NODES) return;
  int l = threadIdx.x & 63;
  int b = l >> 2, o2 = (l & 3) * 2;
  int start = offsets[n], cnt = deg[n];
  float acc0 = 0.f, acc1 = 0.f;
  int k = 0;
  for (; k + 2 <= cnt; k += 2) {
    int4 rA = rec[start + k];
    int4 rB = rec[start + k + 1];
    uint4 uA = *(const uint4*)(h0b + (long)rA.x * HDIM + b * 8);
    uint4 uB = *(const uint4*)(h0b + (long)rB.x * HDIM + b * 8);
    const float* WA = W + ((rA.y * NBLK + b) * 8) * 8 + o2;
    const float* WB = W + ((rB.y * NBLK + b) * 8) * 8 + o2;
    float nA = __int_as_float(rA.z), nB = __int_as_float(rB.z);
    float hA[8] = {bf_lo(uA.x), bf_hi(uA.x), bf_lo(uA.y), bf_hi(uA.y),
                   bf_lo(uA.z), bf_hi(uA.z), bf_lo(uA.w), bf_hi(uA.w)};
    float hB[8] = {bf_lo(uB.x), bf_hi(uB.x), bf_lo(uB.y), bf_hi(uB.y),
                   bf_lo(uB.z), bf_hi(uB.z), bf_lo(uB.w), bf_hi(uB.w)};
    float p0 = 0.f, p1 = 0.f, q0 = 0.f, q1 = 0.f;
#pragma unroll
    for (int i = 0; i < 8; ++i) {
      float2 wa = *(const float2*)(WA + i * 8);
      float2 wb = *(const float2*)(WB + i * 8);
      p0 = fmaf(hA[i], wa.x, p0);
      p1 = fmaf(hA[i], wa.y, p1);
      q0 = fmaf(hB[i], wb.x, q0);
      q1 = fmaf(hB[i], wb.y, q1);
    }
    acc0 = fmaf(p0, nA, acc0);
    acc1 = fmaf(p1, nA, acc1);
    acc0 = fmaf(q0, nB, acc0);
    acc1 = fmaf(q1, nB, acc1);
  }
  if (k < cnt) {
    int4 rA = rec[start + k];
    uint4 uA = *(const uint4*)(h0b + (long)rA.x * HDIM + b * 8);
    const float* WA = W + ((rA.y * NBLK + b) * 8) * 8 + o2;
    float nA = __int_as_float(rA.z);
    float hA[8] = {bf_lo(uA.x), bf_hi(uA.x), bf_lo(uA.y), bf_hi(uA.y),
                   bf_lo(uA.z), bf_hi(uA.z), bf_lo(uA.w), bf_hi(uA.w)};
    float p0 = 0.f, p1 = 0.f;
#pragma unroll
    for (int i = 0; i < 8; ++i) {
      float2 wa = *(const float2*)(WA + i * 8);
      p0 = fmaf(hA[i], wa.x, p0);
      p1 = fmaf(hA[i], wa.y, p1);
    }
    acc0 = fmaf(p0, nA, acc0);
    acc1 = fmaf(p1, nA, acc1);
  }
  float2 res = {acc0, acc1};
  *(float2*)(agg + (long)n * HDIM + l * 2) = res;
}

// ================= Layer-2 aggregation: one wave per node =================
// lane l: block b = l>>2, cols o4 = (l&3)*4 (16 blocks * 16 cols = 256)
__global__ __launch_bounds__(256) void agg_layer2(
    const int4* __restrict__ rec, const int* __restrict__ offsets,
    const int* __restrict__ deg, const ushort_t* __restrict__ h1b,
    const float* __restrict__ W, float* __restrict__ agg) {
  int n = blockIdx.x * 4 + (threadIdx.x >> 6);
  if (n >= N_NODES) return;
  int l = threadIdx.x & 63;
  int b = l >> 2, o4 = (l & 3) * 4;
  int start = offsets[n], cnt = deg[n];
  float ax = 0.f, ay = 0.f, az = 0.f, aw = 0.f;
  int k = 0;
  for (; k + 2 <= cnt; k += 2) {
    int4 rA = rec[start + k];
    int4 rB = rec[start + k + 1];
    uint4 uA = *(const uint4*)(h1b + (long)rA.x * HDIM + b * 8);
    uint4 uB = *(const uint4*)(h1b + (long)rB.x * HDIM + b * 8);
    const float* WA = W + ((rA.y * NBLK + b) * 8) * 16 + o4;
    const float* WB = W + ((rB.y * NBLK + b) * 8) * 16 + o4;
    float nA = __int_as_float(rA.z), nB = __int_as_float(rB.z);
    float hA[8] = {bf_lo(uA.x), bf_hi(uA.x), bf_lo(uA.y), bf_hi(uA.y),
                   bf_lo(uA.z), bf_hi(uA.z), bf_lo(uA.w), bf_hi(uA.w)};
    float hB[8] = {bf_lo(uB.x), bf_hi(uB.x), bf_lo(uB.y), bf_hi(uB.y),
                   bf_lo(uB.z), bf_hi(uB.z), bf_lo(uB.w), bf_hi(uB.w)};
    float px = 0.f, py = 0.f, pz = 0.f, pw = 0.f;
    float qx = 0.f, qy = 0.f, qz = 0.f, qw = 0.f;
#pragma unroll
    for (int i = 0; i < 8; ++i) {
      float4 wa = *(const float4*)(WA + i * 16);
      float4 wb = *(const float4*)(WB + i * 16);
      px = fmaf(hA[i], wa.x, px);
      py = fmaf(hA[i], wa.y, py);
      pz = fmaf(hA[i], wa.z, pz);
      pw = fmaf(hA[i], wa.w, pw);
      qx = fmaf(hB[i], wb.x, qx);
      qy = fmaf(hB[i], wb.y, qy);
      qz = fmaf(hB[i], wb.z, qz);
      qw = fmaf(hB[i], wb.w, qw);
    }
    ax = fmaf(px, nA, ax);
    ay = fmaf(py, nA, ay);
    az = fmaf(pz, nA, az);
    aw = fmaf(pw, nA, aw);
    ax = fmaf(qx, nB, ax);
    ay = fmaf(qy, nB, ay);
    az = fmaf(qz, nB, az);
    aw = fmaf(qw, nB, aw);
  }
  if (k < cnt) {
    int4 rA = rec[start + k];
    uint4 uA = *(const uint4*)(h1b + (long)rA.x * HDIM + b * 8);
    const float* WA = W + ((rA.y * NBLK + b) * 8) * 16 + o4;
    float nA = __int_as_float(rA.z);
    float hA[8] = {bf_lo(uA.x), bf_hi(uA.x), bf_lo(uA.y), bf_hi(uA.y),
                   bf_lo(uA.z), bf_hi(uA.z), bf_lo(uA.w), bf_hi(uA.w)};
    float px = 0.f, py = 0.f, pz = 0.f, pw = 0.f;
#pragma unroll
    for (int i = 0; i < 8; ++i) {
      float4 wa = *(const float4*)(WA + i * 16);
      px = fmaf(hA[i], wa.x, px);
      py = fmaf(hA[i], wa.y, py);
      pz = fmaf(hA[i], wa.z, pz);
      pw = fmaf(hA[i], wa.w, pw);
    }
    ax = fmaf(px, nA, ax);
    ay = fmaf(py, nA, ay);
    az = fmaf(pz, nA, az);
    aw = fmaf(pw, nA, aw);
  }
  float4 res = {ax, ay, az, aw};
  *(float4*)(agg + (long)n * 256 + l * 4) = res;
}

// ================= Node kernels (dense self-loop + epilogue) =================
__global__ __launch_bounds__(256) void node_layer1(
    const int* __restrict__ node_ids, const float* __restrict__ emb,
    const float* __restrict__ loop1, const float* __restrict__ agg1,
    const float* __restrict__ bias, ushort_t* __restrict__ h1b) {
  __shared__ float L[HDIM * HDIM];
  __shared__ float hs[2][HDIM];
  for (int idx = threadIdx.x; idx < HDIM * HDIM; idx += 256) L[idx] = loop1[idx];
  __syncthreads();
  int o = threadIdx.x & 127;
  int sub = threadIdx.x >> 7;
  for (int base = blockIdx.x * 2; base < N_NODES; base += gridDim.x * 2) {
    int n = base + sub;
    if (n < N_NODES) hs[sub][o] = emb[(long)node_ids[n] * HDIM + o];
    __syncthreads();
    if (n < N_NODES) {
      float acc = 0.f;
#pragma unroll
      for (int i = 0; i < HDIM; ++i) acc = fmaf(hs[sub][i], L[i * HDIM + o], acc);
      float v = acc + bias[o] + agg1[(long)n * HDIM + o];
      h1b[(long)n * HDIM + o] = f2bf(fmaxf(v, 0.f));
    }
    __syncthreads();
  }
}

__global__ __launch_bounds__(256) void node_layer2a(
    const ushort_t* __restrict__ h1b, const float* __restrict__ loop2,
    const float* __restrict__ agg2, const float* __restrict__ bias2,
    float* __restrict__ outm) {
  __shared__ float L[HDIM * HDIM];
  __shared__ float hs[2][HDIM];
  for (int idx = threadIdx.x; idx < HDIM * HDIM; idx += 256) {
    int i = idx >> 7, oo = idx & 127;
    L[idx] = loop2[i * 256 + oo];
  }
  __syncthreads();
  int o = threadIdx.x & 127;
  int sub = threadIdx.x >> 7;
  for (int base = blockIdx.x * 2; base < N_NODES; base += gridDim.x * 2) {
    int n = base + sub;
    if (n < N_NODES)
      hs[sub][o] = __uint_as_float((uint_t)h1b[(long)n * HDIM + o] << 16);
    __syncthreads();
    if (n < N_NODES) {
      float acc = 0.f;
#pragma unroll
      for (int i = 0; i < HDIM; ++i) acc = fmaf(hs[sub][i], L[i * HDIM + o], acc);
      outm[(long)n * HDIM + o] = acc + bias2[o] + agg2[(long)n * 256 + o];
    }
    __syncthreads();
  }
}

__global__ __launch_bounds__(256) void node_layer2b(
    const ushort_t* __restrict__ h1b, const float* __restrict__ loop2,
    const float* __restrict__ agg2, const float* __restrict__ bias2,
    const float* __restrict__ eps, float* __restrict__ out) {
  __shared__ float L[HDIM * HDIM];
  __shared__ float hs[2][HDIM];
  for (int idx = threadIdx.x; idx < HDIM * HDIM; idx += 256) {
    int i = idx >> 7, oo = idx & 127;
    L[idx] = loop2[i * 256 + 128 + oo];
  }
  __syncthreads();
  int o = threadIdx.x & 127;
  int sub = threadIdx.x >> 7;
  for (int base = blockIdx.x * 2; base < N_NODES; base += gridDim.x * 2) {
    int n = base + sub;
    if (n < N_NODES)
      hs[sub][o] = __uint_as_float((uint_t)h1b[(long)n * HDIM + o] << 16);
    __syncthreads();
    if (n < N_NODES) {
      float acc = 0.f;
#pragma unroll
      for (int i = 0; i < HDIM; ++i) acc = fmaf(hs[sub][i], L[i * HDIM + o], acc);
      float hv = acc + bias2[128 + o] + agg2[(long)n * 256 + 128 + o];
      float sp = fmaxf(hv, 0.f) + log1pf(expf(-fabsf(hv)));
      float var = sp + 1e-8f;
      long off = (long)n * HDIM + o;
      out[off] = out[off] + sqrtf(var) * eps[off];
    }
    __syncthreads();
  }
}

extern "C" void kernel_launch(void* const* d_in, const int* in_sizes, int n_in,
                              void* d_out, int out_size, void* d_ws, size_t ws_size,
                              hipStream_t stream) {
  const int* node_ids = (const int*)d_in[0];
  const int* src      = (const int*)d_in[1];
  const int* dst      = (const int*)d_in[2];
  const int* etype    = (const int*)d_in[3];
  const float* norm   = (const float*)d_in[4];
  const float* emb    = (const float*)d_in[5];
  const float* W1     = (const float*)d_in[6];
  const float* loop1  = (const float*)d_in[7];
  const float* b1     = (const float*)d_in[8];
  const float* W2     = (const float*)d_in[9];
  const float* loop2  = (const float*)d_in[10];
  const float* b2     = (const float*)d_in[11];
  const float* eps    = (const float*)d_in[12];
  float* out = (float*)d_out;

  char* ws = (char*)d_ws;
  size_t off = 0;
  int* deg       = (int*)(ws + off); off += (size_t)N_NODES * 4;
  int* offsets   = (int*)(ws + off); off += (size_t)N_NODES * 4;
  int* cursor    = (int*)(ws + off); off += (size_t)N_NODES * 4;
  int4* rec      = (int4*)(ws + off); off += (size_t)N_EDGES * 16;
  float* agg2    = (float*)(ws + off); off += (size_t)N_NODES * 256 * 4;
  ushort_t* h0b  = (ushort_t*)(ws + off); off += (size_t)N_NODES * HDIM * 2;
  ushort_t* h1b  = (ushort_t*)(ws + off); off += (size_t)N_NODES * HDIM * 2;
  float* agg1 = out;  // agg1 lives in d_out (dead before node_layer2a writes)

  // ---- CSR build + bf16 feature copy ----
  hipMemsetAsync(deg, 0, (size_t)N_NODES * 4, stream);
  hipMemsetAsync(cursor, 0, (size_t)N_NODES * 4, stream);
  hist_deg<<<(N_EDGES + 255) / 256, 256, 0, stream>>>(dst, deg);
  scan_offsets<<<1, 1024, 0, stream>>>(deg, offsets);
  scatter_rec<<<(N_EDGES + 255) / 256, 256, 0, stream>>>(src, dst, etype, norm,
                                                         offsets, cursor, rec);
  conv_h0<<<(N_NODES * HDIM + 255) / 256, 256, 0, stream>>>(node_ids, emb, h0b);

  // ---- layer 1 ----
  agg_layer1<<<(N_NODES + 3) / 4, 256, 0, stream>>>(rec, offsets, deg, h0b, W1, agg1);
  node_layer1<<<512, 256, 0, stream>>>(node_ids, emb, loop1, agg1, b1, h1b);

  // ---- layer 2 ----
  agg_layer2<<<(N_NODES + 3) / 4, 256, 0, stream>>>(rec, offsets, deg, h1b, W2, agg2);
  node_layer2a<<<512, 256, 0, stream>>>(h1b, loop2, agg2, b2, out);
  node_layer2b<<<512, 256, 0, stream>>>(h1b, loop2, agg2, b2, eps, out);
}

// Round 4
// 1733.954 us; speedup vs baseline: 1.7125x; 1.1217x over previous
//
#include <hip/hip_runtime.h>
#include <math.h>

#define N_NODES 100000
#define N_EDGES 1600000
#define HDIM 128
#define NBLK 16
#define NREL 200

typedef unsigned short ushort_t;
typedef unsigned int uint_t;

__device__ __forceinline__ ushort_t f2bf(float f) {
  uint_t u = __float_as_uint(f);
  u = (u + 0x7fffu + ((u >> 16) & 1u)) >> 16;  // round-to-nearest-even
  return (ushort_t)u;
}
__device__ __forceinline__ float bf_lo(uint_t w) { return __uint_as_float(w << 16); }
__device__ __forceinline__ float bf_hi(uint_t w) { return __uint_as_float(w & 0xffff0000u); }

// ================= CSR build (dst -> packed edge records) =================
__global__ __launch_bounds__(256) void hist_deg(const int* __restrict__ dst,
                                                int* __restrict__ deg) {
  int e = blockIdx.x * 256 + threadIdx.x;
  if (e < N_EDGES) atomicAdd(&deg[dst[e]], 1);
}

__global__ __launch_bounds__(1024) void scan_offsets(const int* __restrict__ deg,
                                                     int* __restrict__ offsets) {
  __shared__ int wsum[16];
  __shared__ int carry_s;
  int tid = threadIdx.x, lane = tid & 63, wid = tid >> 6;
  if (tid == 0) carry_s = 0;
  __syncthreads();
  for (int base = 0; base < N_NODES; base += 1024) {
    int i = base + tid;
    int v = (i < N_NODES) ? deg[i] : 0;
    int x = v;
#pragma unroll
    for (int s = 1; s < 64; s <<= 1) {
      int t = __shfl_up(x, s);
      if (lane >= s) x += t;
    }
    if (lane == 63) wsum[wid] = x;
    __syncthreads();
    if (wid == 0) {
      int y = (lane < 16) ? wsum[lane] : 0;
#pragma unroll
      for (int s = 1; s < 16; s <<= 1) {
        int t = __shfl_up(y, s);
        if (lane >= s) y += t;
      }
      if (lane < 16) wsum[lane] = y;
    }
    __syncthreads();
    int carry = carry_s;
    int wbase = (wid > 0) ? wsum[wid - 1] : 0;
    if (i < N_NODES) offsets[i] = carry + wbase + (x - v);
    __syncthreads();
    if (tid == 0) carry_s = carry + wsum[15];
    __syncthreads();
  }
}

__global__ __launch_bounds__(256) void scatter_rec(
    const int* __restrict__ src, const int* __restrict__ dst,
    const int* __restrict__ etype, const float* __restrict__ norm,
    const int* __restrict__ offsets, int* __restrict__ cursor,
    int4* __restrict__ rec) {
  int e = blockIdx.x * 256 + threadIdx.x;
  if (e >= N_EDGES) return;
  int d = dst[e];
  int pos = offsets[d] + atomicAdd(&cursor[d], 1);
  rec[pos] = make_int4(src[e], etype[e], __float_as_int(norm[e]), 0);
}

// bf16 copy of gathered embeddings
__global__ __launch_bounds__(256) void conv_h0(const int* __restrict__ node_ids,
                                               const float* __restrict__ emb,
                                               ushort_t* __restrict__ h0b) {
  long gid = (long)blockIdx.x * 256 + threadIdx.x;
  if (gid >= (long)N_NODES * HDIM) return;
  int n = (int)(gid >> 7);
  int o = (int)(gid & 127);
  h0b[gid] = f2bf(emb[(long)node_ids[n] * HDIM + o]);
}

// W1 (R,NB,8,8) fp32 -> Wb1 [rb][g(4)][i(8)][c(2)] bf16, o = g*2+c
__global__ __launch_bounds__(256) void conv_w1(const float* __restrict__ W,
                                               ushort_t* __restrict__ Wb) {
  int idx = blockIdx.x * 256 + threadIdx.x;
  if (idx >= NREL * NBLK * 64) return;
  int rb = idx >> 6, ci = idx & 63;
  int i = ci >> 3, o = ci & 7;
  int g = o >> 1, c = o & 1;
  Wb[((rb * 4 + g) * 8 + i) * 2 + c] = f2bf(W[idx]);
}

// W2 (R,NB,8,16) fp32 -> Wb2 [rb][g(4)][i(8)][c(4)] bf16, o = g*4+c
__global__ __launch_bounds__(256) void conv_w2(const float* __restrict__ W,
                                               ushort_t* __restrict__ Wb) {
  int idx = blockIdx.x * 256 + threadIdx.x;
  if (idx >= NREL * NBLK * 128) return;
  int rb = idx >> 7, ci = idx & 127;
  int i = ci >> 4, o = ci & 15;
  int g = o >> 2, c = o & 3;
  Wb[((rb * 4 + g) * 8 + i) * 4 + c] = f2bf(W[idx]);
}

// ================= Layer-1 aggregation: one wave per node =================
// lane l: block b = l>>2, col-group g = l&3 (cols g*2, g*2+1)
__device__ __forceinline__ void edge1_compute(int4 r, int b, int g,
                                              const ushort_t* __restrict__ h0b,
                                              const ushort_t* __restrict__ Wb,
                                              float& acc0, float& acc1) {
  uint4 u = *(const uint4*)(h0b + (long)r.x * HDIM + b * 8);
  const uint4* Wp = (const uint4*)(Wb + ((size_t)(r.y * NBLK + b) * 4 + g) * 16);
  uint4 w0 = Wp[0], w1 = Wp[1];
  float h0 = bf_lo(u.x), h1 = bf_hi(u.x), h2 = bf_lo(u.y), h3 = bf_hi(u.y);
  float h4 = bf_lo(u.z), h5 = bf_hi(u.z), h6 = bf_lo(u.w), h7 = bf_hi(u.w);
  float p0 = 0.f, p1 = 0.f;
#define STEP1(hh, w) p0 = fmaf(hh, bf_lo(w), p0); p1 = fmaf(hh, bf_hi(w), p1);
  STEP1(h0, w0.x) STEP1(h1, w0.y) STEP1(h2, w0.z) STEP1(h3, w0.w)
  STEP1(h4, w1.x) STEP1(h5, w1.y) STEP1(h6, w1.z) STEP1(h7, w1.w)
#undef STEP1
  float nn = __int_as_float(r.z);
  acc0 = fmaf(p0, nn, acc0);
  acc1 = fmaf(p1, nn, acc1);
}

__global__ __launch_bounds__(256) void agg_layer1(
    const int4* __restrict__ rec, const int* __restrict__ offsets,
    const int* __restrict__ deg, const ushort_t* __restrict__ h0b,
    const ushort_t* __restrict__ Wb, float* __restrict__ agg) {
  int n = blockIdx.x * 4 + (threadIdx.x >> 6);
  if (n >= N_NODES) return;
  int l = threadIdx.x & 63;
  int b = l >> 2, g = l & 3;
  int start = offsets[n], cnt = deg[n];
  float acc0 = 0.f, acc1 = 0.f;
  int k = 0;
  for (; k + 4 <= cnt; k += 4) {
    int4 r0 = rec[start + k];
    int4 r1 = rec[start + k + 1];
    int4 r2 = rec[start + k + 2];
    int4 r3 = rec[start + k + 3];
    edge1_compute(r0, b, g, h0b, Wb, acc0, acc1);
    edge1_compute(r1, b, g, h0b, Wb, acc0, acc1);
    edge1_compute(r2, b, g, h0b, Wb, acc0, acc1);
    edge1_compute(r3, b, g, h0b, Wb, acc0, acc1);
  }
  for (; k < cnt; ++k) {
    int4 r0 = rec[start + k];
    edge1_compute(r0, b, g, h0b, Wb, acc0, acc1);
  }
  float2 res = {acc0, acc1};
  *(float2*)(agg + (long)n * HDIM + l * 2) = res;
}

// ================= Layer-2 aggregation: one wave per node =================
// lane l: block b = l>>2, col-group g = l&3 (cols g*4..g*4+3)
__device__ __forceinline__ void edge2_compute(int4 r, int b, int g,
                                              const ushort_t* __restrict__ h1b,
                                              const ushort_t* __restrict__ Wb,
                                              float& ax, float& ay, float& az, float& aw) {
  uint4 u = *(const uint4*)(h1b + (long)r.x * HDIM + b * 8);
  const uint4* Wp = (const uint4*)(Wb + ((size_t)(r.y * NBLK + b) * 4 + g) * 32);
  uint4 q0 = Wp[0], q1 = Wp[1], q2 = Wp[2], q3 = Wp[3];
  float h0 = bf_lo(u.x), h1 = bf_hi(u.x), h2 = bf_lo(u.y), h3 = bf_hi(u.y);
  float h4 = bf_lo(u.z), h5 = bf_hi(u.z), h6 = bf_lo(u.w), h7 = bf_hi(u.w);
  float px = 0.f, py = 0.f, pz = 0.f, pw = 0.f;
#define STEP2(hh, wa, wb)                                       \
  px = fmaf(hh, bf_lo(wa), px); py = fmaf(hh, bf_hi(wa), py);   \
  pz = fmaf(hh, bf_lo(wb), pz); pw = fmaf(hh, bf_hi(wb), pw);
  STEP2(h0, q0.x, q0.y) STEP2(h1, q0.z, q0.w)
  STEP2(h2, q1.x, q1.y) STEP2(h3, q1.z, q1.w)
  STEP2(h4, q2.x, q2.y) STEP2(h5, q2.z, q2.w)
  STEP2(h6, q3.x, q3.y) STEP2(h7, q3.z, q3.w)
#undef STEP2
  float nn = __int_as_float(r.z);
  ax = fmaf(px, nn, ax);
  ay = fmaf(py, nn, ay);
  az = fmaf(pz, nn, az);
  aw = fmaf(pw, nn, aw);
}

__global__ __launch_bounds__(256) void agg_layer2(
    const int4* __restrict__ rec, const int* __restrict__ offsets,
    const int* __restrict__ deg, const ushort_t* __restrict__ h1b,
    const ushort_t* __restrict__ Wb, float* __restrict__ agg) {
  int n = blockIdx.x * 4 + (threadIdx.x >> 6);
  if (n >= N_NODES) return;
  int l = threadIdx.x & 63;
  int b = l >> 2, g = l & 3;
  int start = offsets[n], cnt = deg[n];
  float ax = 0.f, ay = 0.f, az = 0.f, aw = 0.f;
  int k = 0;
  for (; k + 4 <= cnt; k += 4) {
    int4 r0 = rec[start + k];
    int4 r1 = rec[start + k + 1];
    int4 r2 = rec[start + k + 2];
    int4 r3 = rec[start + k + 3];
    edge2_compute(r0, b, g, h1b, Wb, ax, ay, az, aw);
    edge2_compute(r1, b, g, h1b, Wb, ax, ay, az, aw);
    edge2_compute(r2, b, g, h1b, Wb, ax, ay, az, aw);
    edge2_compute(r3, b, g, h1b, Wb, ax, ay, az, aw);
  }
  for (; k < cnt; ++k) {
    int4 r0 = rec[start + k];
    edge2_compute(r0, b, g, h1b, Wb, ax, ay, az, aw);
  }
  float4 res = {ax, ay, az, aw};
  *(float4*)(agg + (long)n * 256 + l * 4) = res;
}

// ================= Node kernels (dense self-loop + epilogue) =================
__global__ __launch_bounds__(256) void node_layer1(
    const int* __restrict__ node_ids, const float* __restrict__ emb,
    const float* __restrict__ loop1, const float* __restrict__ agg1,
    const float* __restrict__ bias, ushort_t* __restrict__ h1b) {
  __shared__ float L[HDIM * HDIM];
  __shared__ float hs[2][HDIM];
  for (int idx = threadIdx.x; idx < HDIM * HDIM; idx += 256) L[idx] = loop1[idx];
  __syncthreads();
  int o = threadIdx.x & 127;
  int sub = threadIdx.x >> 7;
  for (int base = blockIdx.x * 2; base < N_NODES; base += gridDim.x * 2) {
    int n = base + sub;
    if (n < N_NODES) hs[sub][o] = emb[(long)node_ids[n] * HDIM + o];
    __syncthreads();
    if (n < N_NODES) {
      float acc = 0.f;
#pragma unroll
      for (int i = 0; i < HDIM; ++i) acc = fmaf(hs[sub][i], L[i * HDIM + o], acc);
      float v = acc + bias[o] + agg1[(long)n * HDIM + o];
      h1b[(long)n * HDIM + o] = f2bf(fmaxf(v, 0.f));
    }
    __syncthreads();
  }
}

__global__ __launch_bounds__(256) void node_layer2a(
    const ushort_t* __restrict__ h1b, const float* __restrict__ loop2,
    const float* __restrict__ agg2, const float* __restrict__ bias2,
    float* __restrict__ outm) {
  __shared__ float L[HDIM * HDIM];
  __shared__ float hs[2][HDIM];
  for (int idx = threadIdx.x; idx < HDIM * HDIM; idx += 256) {
    int i = idx >> 7, oo = idx & 127;
    L[idx] = loop2[i * 256 + oo];
  }
  __syncthreads();
  int o = threadIdx.x & 127;
  int sub = threadIdx.x >> 7;
  for (int base = blockIdx.x * 2; base < N_NODES; base += gridDim.x * 2) {
    int n = base + sub;
    if (n < N_NODES)
      hs[sub][o] = __uint_as_float((uint_t)h1b[(long)n * HDIM + o] << 16);
    __syncthreads();
    if (n < N_NODES) {
      float acc = 0.f;
#pragma unroll
      for (int i = 0; i < HDIM; ++i) acc = fmaf(hs[sub][i], L[i * HDIM + o], acc);
      outm[(long)n * HDIM + o] = acc + bias2[o] + agg2[(long)n * 256 + o];
    }
    __syncthreads();
  }
}

__global__ __launch_bounds__(256) void node_layer2b(
    const ushort_t* __restrict__ h1b, const float* __restrict__ loop2,
    const float* __restrict__ agg2, const float* __restrict__ bias2,
    const float* __restrict__ eps, float* __restrict__ out) {
  __shared__ float L[HDIM * HDIM];
  __shared__ float hs[2][HDIM];
  for (int idx = threadIdx.x; idx < HDIM * HDIM; idx += 256) {
    int i = idx >> 7, oo = idx & 127;
    L[idx] = loop2[i * 256 + 128 + oo];
  }
  __syncthreads();
  int o = threadIdx.x & 127;
  int sub = threadIdx.x >> 7;
  for (int base = blockIdx.x * 2; base < N_NODES; base += gridDim.x * 2) {
    int n = base + sub;
    if (n < N_NODES)
      hs[sub][o] = __uint_as_float((uint_t)h1b[(long)n * HDIM + o] << 16);
    __syncthreads();
    if (n < N_NODES) {
      float acc = 0.f;
#pragma unroll
      for (int i = 0; i < HDIM; ++i) acc = fmaf(hs[sub][i], L[i * HDIM + o], acc);
      float hv = acc + bias2[128 + o] + agg2[(long)n * 256 + 128 + o];
      float sp = fmaxf(hv, 0.f) + log1pf(expf(-fabsf(hv)));
      float var = sp + 1e-8f;
      long off = (long)n * HDIM + o;
      out[off] = out[off] + sqrtf(var) * eps[off];
    }
    __syncthreads();
  }
}

extern "C" void kernel_launch(void* const* d_in, const int* in_sizes, int n_in,
                              void* d_out, int out_size, void* d_ws, size_t ws_size,
                              hipStream_t stream) {
  const int* node_ids = (const int*)d_in[0];
  const int* src      = (const int*)d_in[1];
  const int* dst      = (const int*)d_in[2];
  const int* etype    = (const int*)d_in[3];
  const float* norm   = (const float*)d_in[4];
  const float* emb    = (const float*)d_in[5];
  const float* W1     = (const float*)d_in[6];
  const float* loop1  = (const float*)d_in[7];
  const float* b1     = (const float*)d_in[8];
  const float* W2     = (const float*)d_in[9];
  const float* loop2  = (const float*)d_in[10];
  const float* b2     = (const float*)d_in[11];
  const float* eps    = (const float*)d_in[12];
  float* out = (float*)d_out;

  char* ws = (char*)d_ws;
  size_t off = 0;
  int* deg       = (int*)(ws + off); off += (size_t)N_NODES * 4;
  int* offsets   = (int*)(ws + off); off += (size_t)N_NODES * 4;
  int* cursor    = (int*)(ws + off); off += (size_t)N_NODES * 4;
  int4* rec      = (int4*)(ws + off); off += (size_t)N_EDGES * 16;
  float* agg2    = (float*)(ws + off); off += (size_t)N_NODES * 256 * 4;
  ushort_t* h0b  = (ushort_t*)(ws + off); off += (size_t)N_NODES * HDIM * 2;
  ushort_t* h1b  = (ushort_t*)(ws + off); off += (size_t)N_NODES * HDIM * 2;
  ushort_t* Wb1  = (ushort_t*)(ws + off); off += (size_t)NREL * NBLK * 64 * 2;
  ushort_t* Wb2  = (ushort_t*)(ws + off); off += (size_t)NREL * NBLK * 128 * 2;
  float* agg1 = out;  // agg1 lives in d_out (dead before node_layer2a writes)

  // ---- CSR build + bf16 conversions ----
  hipMemsetAsync(deg, 0, (size_t)N_NODES * 4, stream);
  hipMemsetAsync(cursor, 0, (size_t)N_NODES * 4, stream);
  hist_deg<<<(N_EDGES + 255) / 256, 256, 0, stream>>>(dst, deg);
  conv_w1<<<(NREL * NBLK * 64 + 255) / 256, 256, 0, stream>>>(W1, Wb1);
  conv_w2<<<(NREL * NBLK * 128 + 255) / 256, 256, 0, stream>>>(W2, Wb2);
  scan_offsets<<<1, 1024, 0, stream>>>(deg, offsets);
  scatter_rec<<<(N_EDGES + 255) / 256, 256, 0, stream>>>(src, dst, etype, norm,
                                                         offsets, cursor, rec);
  conv_h0<<<(N_NODES * HDIM + 255) / 256, 256, 0, stream>>>(node_ids, emb, h0b);

  // ---- layer 1 ----
  agg_layer1<<<(N_NODES + 3) / 4, 256, 0, stream>>>(rec, offsets, deg, h0b, Wb1, agg1);
  node_layer1<<<512, 256, 0, stream>>>(node_ids, emb, loop1, agg1, b1, h1b);

  // ---- layer 2 ----
  agg_layer2<<<(N_NODES + 3) / 4, 256, 0, stream>>>(rec, offsets, deg, h1b, Wb2, agg2);
  node_layer2a<<<512, 256, 0, stream>>>(h1b, loop2, agg2, b2, out);
  node_layer2b<<<512, 256, 0, stream>>>(h1b, loop2, agg2, b2, eps, out);
}

// Round 5
// 1441.591 us; speedup vs baseline: 2.0598x; 1.2028x over previous
//
#include <hip/hip_runtime.h>
#include <math.h>

#define N_NODES 100000
#define N_EDGES 1600000
#define HDIM 128
#define NBLK 16
#define NREL 200

typedef unsigned short ushort_t;
typedef unsigned int uint_t;

__device__ __forceinline__ ushort_t f2bf(float f) {
  uint_t u = __float_as_uint(f);
  u = (u + 0x7fffu + ((u >> 16) & 1u)) >> 16;  // round-to-nearest-even
  return (ushort_t)u;
}
__device__ __forceinline__ float bf_lo(uint_t w) { return __uint_as_float(w << 16); }
__device__ __forceinline__ float bf_hi(uint_t w) { return __uint_as_float(w & 0xffff0000u); }

// ================= CSR build (dst -> packed edge records) =================
__global__ __launch_bounds__(256) void hist_deg(const int* __restrict__ dst,
                                                int* __restrict__ deg) {
  int e = blockIdx.x * 256 + threadIdx.x;
  if (e < N_EDGES) atomicAdd(&deg[dst[e]], 1);
}

__global__ __launch_bounds__(1024) void scan_offsets(const int* __restrict__ deg,
                                                     int* __restrict__ offsets) {
  __shared__ int wsum[16];
  __shared__ int carry_s;
  int tid = threadIdx.x, lane = tid & 63, wid = tid >> 6;
  if (tid == 0) carry_s = 0;
  __syncthreads();
  for (int base = 0; base < N_NODES; base += 1024) {
    int i = base + tid;
    int v = (i < N_NODES) ? deg[i] : 0;
    int x = v;
#pragma unroll
    for (int s = 1; s < 64; s <<= 1) {
      int t = __shfl_up(x, s);
      if (lane >= s) x += t;
    }
    if (lane == 63) wsum[wid] = x;
    __syncthreads();
    if (wid == 0) {
      int y = (lane < 16) ? wsum[lane] : 0;
#pragma unroll
      for (int s = 1; s < 16; s <<= 1) {
        int t = __shfl_up(y, s);
        if (lane >= s) y += t;
      }
      if (lane < 16) wsum[lane] = y;
    }
    __syncthreads();
    int carry = carry_s;
    int wbase = (wid > 0) ? wsum[wid - 1] : 0;
    if (i < N_NODES) offsets[i] = carry + wbase + (x - v);
    __syncthreads();
    if (tid == 0) carry_s = carry + wsum[15];
    __syncthreads();
  }
}

__global__ __launch_bounds__(256) void scatter_rec(
    const int* __restrict__ src, const int* __restrict__ dst,
    const int* __restrict__ etype, const float* __restrict__ norm,
    const int* __restrict__ offsets, int* __restrict__ cursor,
    int4* __restrict__ rec) {
  int e = blockIdx.x * 256 + threadIdx.x;
  if (e >= N_EDGES) return;
  int d = dst[e];
  int pos = offsets[d] + atomicAdd(&cursor[d], 1);
  rec[pos] = make_int4(src[e], etype[e], __float_as_int(norm[e]), 0);
}

// bf16 copy of gathered embeddings
__global__ __launch_bounds__(256) void conv_h0(const int* __restrict__ node_ids,
                                               const float* __restrict__ emb,
                                               ushort_t* __restrict__ h0b) {
  long gid = (long)blockIdx.x * 256 + threadIdx.x;
  if (gid >= (long)N_NODES * HDIM) return;
  int n = (int)(gid >> 7);
  int o = (int)(gid & 127);
  h0b[gid] = f2bf(emb[(long)node_ids[n] * HDIM + o]);
}

// W1 (R,NB,8,8) fp32 -> Wb1 [rb][g(4)][i(8)][c(2)] bf16, o = g*2+c
__global__ __launch_bounds__(256) void conv_w1(const float* __restrict__ W,
                                               ushort_t* __restrict__ Wb) {
  int idx = blockIdx.x * 256 + threadIdx.x;
  if (idx >= NREL * NBLK * 64) return;
  int rb = idx >> 6, ci = idx & 63;
  int i = ci >> 3, o = ci & 7;
  int g = o >> 1, c = o & 1;
  Wb[((rb * 4 + g) * 8 + i) * 2 + c] = f2bf(W[idx]);
}

// W2 (R,NB,8,16) fp32 -> Wb2 [rb][g(4)][i(8)][c(4)] bf16, o = g*4+c
__global__ __launch_bounds__(256) void conv_w2(const float* __restrict__ W,
                                               ushort_t* __restrict__ Wb) {
  int idx = blockIdx.x * 256 + threadIdx.x;
  if (idx >= NREL * NBLK * 128) return;
  int rb = idx >> 7, ci = idx & 127;
  int i = ci >> 4, o = ci & 15;
  int g = o >> 2, c = o & 3;
  Wb[((rb * 4 + g) * 8 + i) * 4 + c] = f2bf(W[idx]);
}

// ================= Layer-1 aggregation: one wave per node =================
// lane l: block b = l>>2, col-group g = l&3 (cols g*2, g*2+1)
__global__ __launch_bounds__(256, 4) void agg_layer1(
    const int4* __restrict__ rec, const int* __restrict__ offsets,
    const int* __restrict__ deg, const ushort_t* __restrict__ h0b,
    const ushort_t* __restrict__ Wb, float* __restrict__ agg) {
  int n = blockIdx.x * 4 + (threadIdx.x >> 6);
  if (n >= N_NODES) return;
  int l = threadIdx.x & 63;
  int b = l >> 2, g = l & 3;
  int start = offsets[n], cnt = deg[n];
  float acc0 = 0.f, acc1 = 0.f;
  for (int c = 0; c < cnt; c += 64) {
    int m = min(64, cnt - c);
    int4 r = make_int4(0, 0, 0, 0);
    if (l < m) r = rec[start + c + l];
    // prologue: edge 0 loads
    int s0 = __shfl(r.x, 0);
    int t0 = __shfl(r.y, 0);
    uint4 u = *(const uint4*)(h0b + (long)s0 * HDIM + b * 8);
    const uint4* Wp = (const uint4*)(Wb + ((size_t)(t0 * NBLK + b) * 4 + g) * 16);
    uint4 w0 = Wp[0], w1 = Wp[1];
    for (int k = 0; k < m; ++k) {
      float nn = __uint_as_float((uint_t)__shfl(r.z, k));
      uint4 un, w0n, w1n;
      bool more = (k + 1 < m);
      if (more) {
        int s1 = __shfl(r.x, k + 1);
        int t1 = __shfl(r.y, k + 1);
        un = *(const uint4*)(h0b + (long)s1 * HDIM + b * 8);
        const uint4* Wn = (const uint4*)(Wb + ((size_t)(t1 * NBLK + b) * 4 + g) * 16);
        w0n = Wn[0];
        w1n = Wn[1];
      }
      float h0 = bf_lo(u.x), h1 = bf_hi(u.x), h2 = bf_lo(u.y), h3 = bf_hi(u.y);
      float h4 = bf_lo(u.z), h5 = bf_hi(u.z), h6 = bf_lo(u.w), h7 = bf_hi(u.w);
      float p0 = 0.f, p1 = 0.f;
#define STEP1(hh, w) p0 = fmaf(hh, bf_lo(w), p0); p1 = fmaf(hh, bf_hi(w), p1);
      STEP1(h0, w0.x) STEP1(h1, w0.y) STEP1(h2, w0.z) STEP1(h3, w0.w)
      STEP1(h4, w1.x) STEP1(h5, w1.y) STEP1(h6, w1.z) STEP1(h7, w1.w)
#undef STEP1
      acc0 = fmaf(p0, nn, acc0);
      acc1 = fmaf(p1, nn, acc1);
      if (more) {
        u = un;
        w0 = w0n;
        w1 = w1n;
      }
    }
  }
  float2 res = {acc0, acc1};
  *(float2*)(agg + (long)n * HDIM + l * 2) = res;
}

// ================= Layer-2 aggregation: one wave per node =================
// lane l: block b = l>>2, col-group g = l&3 (cols g*4..g*4+3)
__global__ __launch_bounds__(256, 4) void agg_layer2(
    const int4* __restrict__ rec, const int* __restrict__ offsets,
    const int* __restrict__ deg, const ushort_t* __restrict__ h1b,
    const ushort_t* __restrict__ Wb, float* __restrict__ agg) {
  int n = blockIdx.x * 4 + (threadIdx.x >> 6);
  if (n >= N_NODES) return;
  int l = threadIdx.x & 63;
  int b = l >> 2, g = l & 3;
  int start = offsets[n], cnt = deg[n];
  float ax = 0.f, ay = 0.f, az = 0.f, aw = 0.f;
  for (int c = 0; c < cnt; c += 64) {
    int m = min(64, cnt - c);
    int4 r = make_int4(0, 0, 0, 0);
    if (l < m) r = rec[start + c + l];
    // prologue: edge 0 loads
    int s0 = __shfl(r.x, 0);
    int t0 = __shfl(r.y, 0);
    uint4 u = *(const uint4*)(h1b + (long)s0 * HDIM + b * 8);
    const uint4* Wp = (const uint4*)(Wb + ((size_t)(t0 * NBLK + b) * 4 + g) * 32);
    uint4 q0 = Wp[0], q1 = Wp[1], q2 = Wp[2], q3 = Wp[3];
    for (int k = 0; k < m; ++k) {
      float nn = __uint_as_float((uint_t)__shfl(r.z, k));
      uint4 un, q0n, q1n, q2n, q3n;
      bool more = (k + 1 < m);
      if (more) {
        int s1 = __shfl(r.x, k + 1);
        int t1 = __shfl(r.y, k + 1);
        un = *(const uint4*)(h1b + (long)s1 * HDIM + b * 8);
        const uint4* Wn = (const uint4*)(Wb + ((size_t)(t1 * NBLK + b) * 4 + g) * 32);
        q0n = Wn[0];
        q1n = Wn[1];
        q2n = Wn[2];
        q3n = Wn[3];
      }
      float h0 = bf_lo(u.x), h1 = bf_hi(u.x), h2 = bf_lo(u.y), h3 = bf_hi(u.y);
      float h4 = bf_lo(u.z), h5 = bf_hi(u.z), h6 = bf_lo(u.w), h7 = bf_hi(u.w);
      float px = 0.f, py = 0.f, pz = 0.f, pw = 0.f;
#define STEP2(hh, wa, wb)                                       \
  px = fmaf(hh, bf_lo(wa), px); py = fmaf(hh, bf_hi(wa), py);   \
  pz = fmaf(hh, bf_lo(wb), pz); pw = fmaf(hh, bf_hi(wb), pw);
      STEP2(h0, q0.x, q0.y) STEP2(h1, q0.z, q0.w)
      STEP2(h2, q1.x, q1.y) STEP2(h3, q1.z, q1.w)
      STEP2(h4, q2.x, q2.y) STEP2(h5, q2.z, q2.w)
      STEP2(h6, q3.x, q3.y) STEP2(h7, q3.z, q3.w)
#undef STEP2
      ax = fmaf(px, nn, ax);
      ay = fmaf(py, nn, ay);
      az = fmaf(pz, nn, az);
      aw = fmaf(pw, nn, aw);
      if (more) {
        u = un;
        q0 = q0n;
        q1 = q1n;
        q2 = q2n;
        q3 = q3n;
      }
    }
  }
  float4 res = {ax, ay, az, aw};
  *(float4*)(agg + (long)n * 256 + l * 4) = res;
}

// ================= Node kernels (dense self-loop + epilogue) =================
__global__ __launch_bounds__(256) void node_layer1(
    const int* __restrict__ node_ids, const float* __restrict__ emb,
    const float* __restrict__ loop1, const float* __restrict__ agg1,
    const float* __restrict__ bias, ushort_t* __restrict__ h1b) {
  __shared__ float L[HDIM * HDIM];
  __shared__ float hs[2][HDIM];
  for (int idx = threadIdx.x; idx < HDIM * HDIM; idx += 256) L[idx] = loop1[idx];
  __syncthreads();
  int o = threadIdx.x & 127;
  int sub = threadIdx.x >> 7;
  for (int base = blockIdx.x * 2; base < N_NODES; base += gridDim.x * 2) {
    int n = base + sub;
    if (n < N_NODES) hs[sub][o] = emb[(long)node_ids[n] * HDIM + o];
    __syncthreads();
    if (n < N_NODES) {
      float acc = 0.f;
#pragma unroll
      for (int i = 0; i < HDIM; ++i) acc = fmaf(hs[sub][i], L[i * HDIM + o], acc);
      float v = acc + bias[o] + agg1[(long)n * HDIM + o];
      h1b[(long)n * HDIM + o] = f2bf(fmaxf(v, 0.f));
    }
    __syncthreads();
  }
}

__global__ __launch_bounds__(256) void node_layer2a(
    const ushort_t* __restrict__ h1b, const float* __restrict__ loop2,
    const float* __restrict__ agg2, const float* __restrict__ bias2,
    float* __restrict__ outm) {
  __shared__ float L[HDIM * HDIM];
  __shared__ float hs[2][HDIM];
  for (int idx = threadIdx.x; idx < HDIM * HDIM; idx += 256) {
    int i = idx >> 7, oo = idx & 127;
    L[idx] = loop2[i * 256 + oo];
  }
  __syncthreads();
  int o = threadIdx.x & 127;
  int sub = threadIdx.x >> 7;
  for (int base = blockIdx.x * 2; base < N_NODES; base += gridDim.x * 2) {
    int n = base + sub;
    if (n < N_NODES)
      hs[sub][o] = __uint_as_float((uint_t)h1b[(long)n * HDIM + o] << 16);
    __syncthreads();
    if (n < N_NODES) {
      float acc = 0.f;
#pragma unroll
      for (int i = 0; i < HDIM; ++i) acc = fmaf(hs[sub][i], L[i * HDIM + o], acc);
      outm[(long)n * HDIM + o] = acc + bias2[o] + agg2[(long)n * 256 + o];
    }
    __syncthreads();
  }
}

__global__ __launch_bounds__(256) void node_layer2b(
    const ushort_t* __restrict__ h1b, const float* __restrict__ loop2,
    const float* __restrict__ agg2, const float* __restrict__ bias2,
    const float* __restrict__ eps, float* __restrict__ out) {
  __shared__ float L[HDIM * HDIM];
  __shared__ float hs[2][HDIM];
  for (int idx = threadIdx.x; idx < HDIM * HDIM; idx += 256) {
    int i = idx >> 7, oo = idx & 127;
    L[idx] = loop2[i * 256 + 128 + oo];
  }
  __syncthreads();
  int o = threadIdx.x & 127;
  int sub = threadIdx.x >> 7;
  for (int base = blockIdx.x * 2; base < N_NODES; base += gridDim.x * 2) {
    int n = base + sub;
    if (n < N_NODES)
      hs[sub][o] = __uint_as_float((uint_t)h1b[(long)n * HDIM + o] << 16);
    __syncthreads();
    if (n < N_NODES) {
      float acc = 0.f;
#pragma unroll
      for (int i = 0; i < HDIM; ++i) acc = fmaf(hs[sub][i], L[i * HDIM + o], acc);
      float hv = acc + bias2[128 + o] + agg2[(long)n * 256 + 128 + o];
      float sp = fmaxf(hv, 0.f) + log1pf(expf(-fabsf(hv)));
      float var = sp + 1e-8f;
      long off = (long)n * HDIM + o;
      out[off] = out[off] + sqrtf(var) * eps[off];
    }
    __syncthreads();
  }
}

extern "C" void kernel_launch(void* const* d_in, const int* in_sizes, int n_in,
                              void* d_out, int out_size, void* d_ws, size_t ws_size,
                              hipStream_t stream) {
  const int* node_ids = (const int*)d_in[0];
  const int* src      = (const int*)d_in[1];
  const int* dst      = (const int*)d_in[2];
  const int* etype    = (const int*)d_in[3];
  const float* norm   = (const float*)d_in[4];
  const float* emb    = (const float*)d_in[5];
  const float* W1     = (const float*)d_in[6];
  const float* loop1  = (const float*)d_in[7];
  const float* b1     = (const float*)d_in[8];
  const float* W2     = (const float*)d_in[9];
  const float* loop2  = (const float*)d_in[10];
  const float* b2     = (const float*)d_in[11];
  const float* eps    = (const float*)d_in[12];
  float* out = (float*)d_out;

  char* ws = (char*)d_ws;
  size_t off = 0;
  int* deg       = (int*)(ws + off); off += (size_t)N_NODES * 4;
  int* offsets   = (int*)(ws + off); off += (size_t)N_NODES * 4;
  int* cursor    = (int*)(ws + off); off += (size_t)N_NODES * 4;
  int4* rec      = (int4*)(ws + off); off += (size_t)N_EDGES * 16;
  float* agg2    = (float*)(ws + off); off += (size_t)N_NODES * 256 * 4;
  ushort_t* h0b  = (ushort_t*)(ws + off); off += (size_t)N_NODES * HDIM * 2;
  ushort_t* h1b  = (ushort_t*)(ws + off); off += (size_t)N_NODES * HDIM * 2;
  ushort_t* Wb1  = (ushort_t*)(ws + off); off += (size_t)NREL * NBLK * 64 * 2;
  ushort_t* Wb2  = (ushort_t*)(ws + off); off += (size_t)NREL * NBLK * 128 * 2;
  float* agg1 = out;  // agg1 lives in d_out (dead before node_layer2a writes)

  // ---- CSR build + bf16 conversions ----
  hipMemsetAsync(deg, 0, (size_t)N_NODES * 4, stream);
  hipMemsetAsync(cursor, 0, (size_t)N_NODES * 4, stream);
  hist_deg<<<(N_EDGES + 255) / 256, 256, 0, stream>>>(dst, deg);
  conv_w1<<<(NREL * NBLK * 64 + 255) / 256, 256, 0, stream>>>(W1, Wb1);
  conv_w2<<<(NREL * NBLK * 128 + 255) / 256, 256, 0, stream>>>(W2, Wb2);
  scan_offsets<<<1, 1024, 0, stream>>>(deg, offsets);
  scatter_rec<<<(N_EDGES + 255) / 256, 256, 0, stream>>>(src, dst, etype, norm,
                                                         offsets, cursor, rec);
  conv_h0<<<(N_NODES * HDIM + 255) / 256, 256, 0, stream>>>(node_ids, emb, h0b);

  // ---- layer 1 ----
  agg_layer1<<<(N_NODES + 3) / 4, 256, 0, stream>>>(rec, offsets, deg, h0b, Wb1, agg1);
  node_layer1<<<512, 256, 0, stream>>>(node_ids, emb, loop1, agg1, b1, h1b);

  // ---- layer 2 ----
  agg_layer2<<<(N_NODES + 3) / 4, 256, 0, stream>>>(rec, offsets, deg, h1b, Wb2, agg2);
  node_layer2a<<<512, 256, 0, stream>>>(h1b, loop2, agg2, b2, out);
  node_layer2b<<<512, 256, 0, stream>>>(h1b, loop2, agg2, b2, eps, out);
}

// Round 7
// 1428.874 us; speedup vs baseline: 2.0781x; 1.0089x over previous
//
#include <hip/hip_runtime.h>
#include <math.h>

#define N_NODES 100000
#define N_EDGES 1600000
#define HDIM 128
#define NBLK 16
#define NREL 200

typedef unsigned short ushort_t;
typedef unsigned int uint_t;
typedef _Float16 h2 __attribute__((ext_vector_type(2)));

__device__ __forceinline__ ushort_t f2h(float f) {
  _Float16 h = (_Float16)f;
  return __builtin_bit_cast(unsigned short, h);
}
__device__ __forceinline__ float h2f(ushort_t b) {
  return (float)__builtin_bit_cast(_Float16, b);
}

// acc += a.lo*b.lo + a.hi*b.hi  (packed f16 pairs, f32 accumulate)
#if defined(__has_builtin) && __has_builtin(__builtin_amdgcn_fdot2)
#define FDOT2(accv, au, bu)                                                    \
  accv = __builtin_amdgcn_fdot2(__builtin_bit_cast(h2, au),                    \
                                __builtin_bit_cast(h2, bu), accv, false);
#else
#define FDOT2(accv, au, bu)                                                    \
  {                                                                            \
    h2 av_ = __builtin_bit_cast(h2, au);                                       \
    h2 bv_ = __builtin_bit_cast(h2, bu);                                       \
    accv = fmaf((float)av_[0], (float)bv_[0], accv);                           \
    accv = fmaf((float)av_[1], (float)bv_[1], accv);                           \
  }
#endif

// ================= CSR build (dst -> packed edge records) =================
__global__ __launch_bounds__(256) void hist_deg(const int* __restrict__ dst,
                                                int* __restrict__ deg) {
  int e = blockIdx.x * 256 + threadIdx.x;
  if (e < N_EDGES) atomicAdd(&deg[dst[e]], 1);
}

__global__ __launch_bounds__(1024) void scan_offsets(const int* __restrict__ deg,
                                                     int* __restrict__ offsets) {
  __shared__ int wsum[16];
  __shared__ int carry_s;
  int tid = threadIdx.x, lane = tid & 63, wid = tid >> 6;
  if (tid == 0) carry_s = 0;
  __syncthreads();
  for (int base = 0; base < N_NODES; base += 1024) {
    int i = base + tid;
    int v = (i < N_NODES) ? deg[i] : 0;
    int x = v;
#pragma unroll
    for (int s = 1; s < 64; s <<= 1) {
      int t = __shfl_up(x, s);
      if (lane >= s) x += t;
    }
    if (lane == 63) wsum[wid] = x;
    __syncthreads();
    if (wid == 0) {
      int y = (lane < 16) ? wsum[lane] : 0;
#pragma unroll
      for (int s = 1; s < 16; s <<= 1) {
        int t = __shfl_up(y, s);
        if (lane >= s) y += t;
      }
      if (lane < 16) wsum[lane] = y;
    }
    __syncthreads();
    int carry = carry_s;
    int wbase = (wid > 0) ? wsum[wid - 1] : 0;
    if (i < N_NODES) offsets[i] = carry + wbase + (x - v);
    __syncthreads();
    if (tid == 0) carry_s = carry + wsum[15];
    __syncthreads();
  }
}

__global__ __launch_bounds__(256) void scatter_rec(
    const int* __restrict__ src, const int* __restrict__ dst,
    const int* __restrict__ etype, const float* __restrict__ norm,
    const int* __restrict__ offsets, int* __restrict__ cursor,
    int4* __restrict__ rec) {
  int e = blockIdx.x * 256 + threadIdx.x;
  if (e >= N_EDGES) return;
  int d = dst[e];
  int pos = offsets[d] + atomicAdd(&cursor[d], 1);
  rec[pos] = make_int4(src[e], etype[e], __float_as_int(norm[e]), 0);
}

// f16 copy of gathered embeddings
__global__ __launch_bounds__(256) void conv_h0(const int* __restrict__ node_ids,
                                               const float* __restrict__ emb,
                                               ushort_t* __restrict__ h0h) {
  long gid = (long)blockIdx.x * 256 + threadIdx.x;
  if (gid >= (long)N_NODES * HDIM) return;
  int n = (int)(gid >> 7);
  int o = (int)(gid & 127);
  h0h[gid] = f2h(emb[(long)node_ids[n] * HDIM + o]);
}

// W1 (R,NB,8,8) fp32 -> Wh1 [rb][g(4)][c(2)][ip(4)][hi(2)] f16 (i = ip*2+hi, o = g*2+c)
__global__ __launch_bounds__(256) void conv_w1(const float* __restrict__ W,
                                               ushort_t* __restrict__ Wh) {
  int idx = blockIdx.x * 256 + threadIdx.x;
  if (idx >= NREL * NBLK * 64) return;
  int rb = idx >> 6, i = (idx >> 3) & 7, o = idx & 7;
  int g = o >> 1, c = o & 1, ip = i >> 1, hi = i & 1;
  Wh[(((rb * 4 + g) * 2 + c) * 4 + ip) * 2 + hi] = f2h(W[idx]);
}

// W2 (R,NB,8,16) fp32 -> Wh2 [rb][g(4)][c(4)][ip(4)][hi(2)] f16 (i = ip*2+hi, o = g*4+c)
__global__ __launch_bounds__(256) void conv_w2(const float* __restrict__ W,
                                               ushort_t* __restrict__ Wh) {
  int idx = blockIdx.x * 256 + threadIdx.x;
  if (idx >= NREL * NBLK * 128) return;
  int rb = idx >> 7, i = (idx >> 4) & 7, o = idx & 15;
  int g = o >> 2, c = o & 3, ip = i >> 1, hi = i & 1;
  Wh[(((rb * 4 + g) * 4 + c) * 4 + ip) * 2 + hi] = f2h(W[idx]);
}

// ================= Layer-1 aggregation: one wave per node =================
// lane l: block b = l>>2, col-group g = l&3 (cols g*2, g*2+1)
__global__ __launch_bounds__(256, 4) void agg_layer1(
    const int4* __restrict__ rec, const int* __restrict__ offsets,
    const int* __restrict__ deg, const ushort_t* __restrict__ h0h,
    const ushort_t* __restrict__ Wh, float* __restrict__ agg) {
  int n = blockIdx.x * 4 + (threadIdx.x >> 6);
  if (n >= N_NODES) return;
  int l = threadIdx.x & 63;
  int b = l >> 2, g = l & 3;
  int start = offsets[n], cnt = deg[n];
  float acc0 = 0.f, acc1 = 0.f;

#define LOAD1(U, W0, W1, kk)                                                   \
  {                                                                            \
    int ss = __shfl(r.x, kk), tt = __shfl(r.y, kk);                            \
    U = *(const uint4*)(h0h + ((long)ss << 7) + (b << 3));                     \
    const uint4* Wp =                                                          \
        (const uint4*)(Wh + (((size_t)((tt << 4) + b) << 2) + g) * 16);        \
    W0 = Wp[0];                                                                \
    W1 = Wp[1];                                                                \
  }
#define COMP1(U, W0, W1, kk)                                                   \
  {                                                                            \
    float nn = __uint_as_float((uint_t)__shfl(r.z, kk));                       \
    float p0 = 0.f, p1 = 0.f;                                                  \
    FDOT2(p0, U.x, W0.x) FDOT2(p0, U.y, W0.y)                                  \
    FDOT2(p0, U.z, W0.z) FDOT2(p0, U.w, W0.w)                                  \
    FDOT2(p1, U.x, W1.x) FDOT2(p1, U.y, W1.y)                                  \
    FDOT2(p1, U.z, W1.z) FDOT2(p1, U.w, W1.w)                                  \
    acc0 = fmaf(p0, nn, acc0);                                                 \
    acc1 = fmaf(p1, nn, acc1);                                                 \
  }

  for (int c0 = 0; c0 < cnt; c0 += 64) {
    int m = min(64, cnt - c0);
    int4 r = make_int4(0, 0, 0, 0);
    if (l < m) r = rec[start + c0 + l];
    uint4 uA, wA0, wA1, uB, wB0, wB1;
    LOAD1(uA, wA0, wA1, 0)
    int k = 0;
    while (true) {
      if (k + 1 < m) LOAD1(uB, wB0, wB1, k + 1)
      COMP1(uA, wA0, wA1, k)
      if (++k >= m) break;
      if (k + 1 < m) LOAD1(uA, wA0, wA1, k + 1)
      COMP1(uB, wB0, wB1, k)
      if (++k >= m) break;
    }
  }
#undef LOAD1
#undef COMP1
  float2 res = {acc0, acc1};
  *(float2*)(agg + (long)n * HDIM + l * 2) = res;
}

// ================= Layer-2 aggregation: one wave per node =================
// lane l: block b = l>>2, col-group g = l&3 (cols g*4..g*4+3)
__global__ __launch_bounds__(256, 4) void agg_layer2(
    const int4* __restrict__ rec, const int* __restrict__ offsets,
    const int* __restrict__ deg, const ushort_t* __restrict__ h1h,
    const ushort_t* __restrict__ Wh, float* __restrict__ agg) {
  int n = blockIdx.x * 4 + (threadIdx.x >> 6);
  if (n >= N_NODES) return;
  int l = threadIdx.x & 63;
  int b = l >> 2, g = l & 3;
  int start = offsets[n], cnt = deg[n];
  float ax = 0.f, ay = 0.f, az = 0.f, aw = 0.f;

#define LOAD2(U, Q0, Q1, Q2, Q3, kk)                                           \
  {                                                                            \
    int ss = __shfl(r.x, kk), tt = __shfl(r.y, kk);                            \
    U = *(const uint4*)(h1h + ((long)ss << 7) + (b << 3));                     \
    const uint4* Wp =                                                          \
        (const uint4*)(Wh + (((size_t)((tt << 4) + b) << 2) + g) * 32);        \
    Q0 = Wp[0];                                                                \
    Q1 = Wp[1];                                                                \
    Q2 = Wp[2];                                                                \
    Q3 = Wp[3];                                                                \
  }
#define COMP2(U, Q0, Q1, Q2, Q3, kk)                                           \
  {                                                                            \
    float nn = __uint_as_float((uint_t)__shfl(r.z, kk));                       \
    float px = 0.f, py = 0.f, pz = 0.f, pw = 0.f;                              \
    FDOT2(px, U.x, Q0.x) FDOT2(px, U.y, Q0.y)                                  \
    FDOT2(px, U.z, Q0.z) FDOT2(px, U.w, Q0.w)                                  \
    FDOT2(py, U.x, Q1.x) FDOT2(py, U.y, Q1.y)                                  \
    FDOT2(py, U.z, Q1.z) FDOT2(py, U.w, Q1.w)                                  \
    FDOT2(pz, U.x, Q2.x) FDOT2(pz, U.y, Q2.y)                                  \
    FDOT2(pz, U.z, Q2.z) FDOT2(pz, U.w, Q2.w)                                  \
    FDOT2(pw, U.x, Q3.x) FDOT2(pw, U.y, Q3.y)                                  \
    FDOT2(pw, U.z, Q3.z) FDOT2(pw, U.w, Q3.w)                                  \
    ax = fmaf(px, nn, ax);                                                     \
    ay = fmaf(py, nn, ay);                                                     \
    az = fmaf(pz, nn, az);                                                     \
    aw = fmaf(pw, nn, aw);                                                     \
  }

  for (int c0 = 0; c0 < cnt; c0 += 64) {
    int m = min(64, cnt - c0);
    int4 r = make_int4(0, 0, 0, 0);
    if (l < m) r = rec[start + c0 + l];
    uint4 uA, qA0, qA1, qA2, qA3, uB, qB0, qB1, qB2, qB3;
    LOAD2(uA, qA0, qA1, qA2, qA3, 0)
    int k = 0;
    while (true) {
      if (k + 1 < m) LOAD2(uB, qB0, qB1, qB2, qB3, k + 1)
      COMP2(uA, qA0, qA1, qA2, qA3, k)
      if (++k >= m) break;
      if (k + 1 < m) LOAD2(uA, qA0, qA1, qA2, qA3, k + 1)
      COMP2(uB, qB0, qB1, qB2, qB3, k)
      if (++k >= m) break;
    }
  }
#undef LOAD2
#undef COMP2
  float4 res = {ax, ay, az, aw};
  *(float4*)(agg + (long)n * 256 + l * 4) = res;
}

// ================= Node kernels (dense self-loop + epilogue) =================
__global__ __launch_bounds__(256) void node_layer1(
    const int* __restrict__ node_ids, const float* __restrict__ emb,
    const float* __restrict__ loop1, const float* __restrict__ agg1,
    const float* __restrict__ bias, ushort_t* __restrict__ h1h) {
  __shared__ float L[HDIM * HDIM];
  __shared__ float hs[2][HDIM];
  for (int idx = threadIdx.x; idx < HDIM * HDIM; idx += 256) L[idx] = loop1[idx];
  __syncthreads();
  int o = threadIdx.x & 127;
  int sub = threadIdx.x >> 7;
  for (int base = blockIdx.x * 2; base < N_NODES; base += gridDim.x * 2) {
    int n = base + sub;
    if (n < N_NODES) hs[sub][o] = emb[(long)node_ids[n] * HDIM + o];
    __syncthreads();
    if (n < N_NODES) {
      float acc = 0.f;
#pragma unroll
      for (int i = 0; i < HDIM; ++i) acc = fmaf(hs[sub][i], L[i * HDIM + o], acc);
      float v = acc + bias[o] + agg1[(long)n * HDIM + o];
      h1h[(long)n * HDIM + o] = f2h(fmaxf(v, 0.f));
    }
    __syncthreads();
  }
}

__global__ __launch_bounds__(256) void node_layer2a(
    const ushort_t* __restrict__ h1h, const float* __restrict__ loop2,
    const float* __restrict__ agg2, const float* __restrict__ bias2,
    float* __restrict__ outm) {
  __shared__ float L[HDIM * HDIM];
  __shared__ float hs[2][HDIM];
  for (int idx = threadIdx.x; idx < HDIM * HDIM; idx += 256) {
    int i = idx >> 7, oo = idx & 127;
    L[idx] = loop2[i * 256 + oo];
  }
  __syncthreads();
  int o = threadIdx.x & 127;
  int sub = threadIdx.x >> 7;
  for (int base = blockIdx.x * 2; base < N_NODES; base += gridDim.x * 2) {
    int n = base + sub;
    if (n < N_NODES) hs[sub][o] = h2f(h1h[(long)n * HDIM + o]);
    __syncthreads();
    if (n < N_NODES) {
      float acc = 0.f;
#pragma unroll
      for (int i = 0; i < HDIM; ++i) acc = fmaf(hs[sub][i], L[i * HDIM + o], acc);
      outm[(long)n * HDIM + o] = acc + bias2[o] + agg2[(long)n * 256 + o];
    }
    __syncthreads();
  }
}

__global__ __launch_bounds__(256) void node_layer2b(
    const ushort_t* __restrict__ h1h, const float* __restrict__ loop2,
    const float* __restrict__ agg2, const float* __restrict__ bias2,
    const float* __restrict__ eps, float* __restrict__ out) {
  __shared__ float L[HDIM * HDIM];
  __shared__ float hs[2][HDIM];
  for (int idx = threadIdx.x; idx < HDIM * HDIM; idx += 256) {
    int i = idx >> 7, oo = idx & 127;
    L[idx] = loop2[i * 256 + 128 + oo];
  }
  __syncthreads();
  int o = threadIdx.x & 127;
  int sub = threadIdx.x >> 7;
  for (int base = blockIdx.x * 2; base < N_NODES; base += gridDim.x * 2) {
    int n = base + sub;
    if (n < N_NODES) hs[sub][o] = h2f(h1h[(long)n * HDIM + o]);
    __syncthreads();
    if (n < N_NODES) {
      float acc = 0.f;
#pragma unroll
      for (int i = 0; i < HDIM; ++i) acc = fmaf(hs[sub][i], L[i * HDIM + o], acc);
      float hv = acc + bias2[128 + o] + agg2[(long)n * 256 + 128 + o];
      float sp = fmaxf(hv, 0.f) + log1pf(expf(-fabsf(hv)));
      float var = sp + 1e-8f;
      long off = (long)n * HDIM + o;
      out[off] = out[off] + sqrtf(var) * eps[off];
    }
    __syncthreads();
  }
}

extern "C" void kernel_launch(void* const* d_in, const int* in_sizes, int n_in,
                              void* d_out, int out_size, void* d_ws, size_t ws_size,
                              hipStream_t stream) {
  const int* node_ids = (const int*)d_in[0];
  const int* src      = (const int*)d_in[1];
  const int* dst      = (const int*)d_in[2];
  const int* etype    = (const int*)d_in[3];
  const float* norm   = (const float*)d_in[4];
  const float* emb    = (const float*)d_in[5];
  const float* W1     = (const float*)d_in[6];
  const float* loop1  = (const float*)d_in[7];
  const float* b1     = (const float*)d_in[8];
  const float* W2     = (const float*)d_in[9];
  const float* loop2  = (const float*)d_in[10];
  const float* b2     = (const float*)d_in[11];
  const float* eps    = (const float*)d_in[12];
  float* out = (float*)d_out;

  char* ws = (char*)d_ws;
  size_t off = 0;
  int* deg       = (int*)(ws + off); off += (size_t)N_NODES * 4;
  int* offsets   = (int*)(ws + off); off += (size_t)N_NODES * 4;
  int* cursor    = (int*)(ws + off); off += (size_t)N_NODES * 4;
  int4* rec      = (int4*)(ws + off); off += (size_t)N_EDGES * 16;
  float* agg2    = (float*)(ws + off); off += (size_t)N_NODES * 256 * 4;
  ushort_t* h0h  = (ushort_t*)(ws + off); off += (size_t)N_NODES * HDIM * 2;
  ushort_t* h1h  = (ushort_t*)(ws + off); off += (size_t)N_NODES * HDIM * 2;
  ushort_t* Wh1  = (ushort_t*)(ws + off); off += (size_t)NREL * NBLK * 64 * 2;
  ushort_t* Wh2  = (ushort_t*)(ws + off); off += (size_t)NREL * NBLK * 128 * 2;
  float* agg1 = out;  // agg1 lives in d_out (dead before node_layer2a writes)

  // ---- CSR build + f16 conversions ----
  hipMemsetAsync(deg, 0, (size_t)N_NODES * 4, stream);
  hipMemsetAsync(cursor, 0, (size_t)N_NODES * 4, stream);
  hist_deg<<<(N_EDGES + 255) / 256, 256, 0, stream>>>(dst, deg);
  conv_w1<<<(NREL * NBLK * 64 + 255) / 256, 256, 0, stream>>>(W1, Wh1);
  conv_w2<<<(NREL * NBLK * 128 + 255) / 256, 256, 0, stream>>>(W2, Wh2);
  scan_offsets<<<1, 1024, 0, stream>>>(deg, offsets);
  scatter_rec<<<(N_EDGES + 255) / 256, 256, 0, stream>>>(src, dst, etype, norm,
                                                         offsets, cursor, rec);
  conv_h0<<<(N_NODES * HDIM + 255) / 256, 256, 0, stream>>>(node_ids, emb, h0h);

  // ---- layer 1 ----
  agg_layer1<<<(N_NODES + 3) / 4, 256, 0, stream>>>(rec, offsets, deg, h0h, Wh1, agg1);
  node_layer1<<<512, 256, 0, stream>>>(node_ids, emb, loop1, agg1, b1, h1h);

  // ---- layer 2 ----
  agg_layer2<<<(N_NODES + 3) / 4, 256, 0, stream>>>(rec, offsets, deg, h1h, Wh2, agg2);
  node_layer2a<<<512, 256, 0, stream>>>(h1h, loop2, agg2, b2, out);
  node_layer2b<<<512, 256, 0, stream>>>(h1h, loop2, agg2, b2, eps, out);
}